// Round 1
// baseline (587.814 us; speedup 1.0000x reference)
//
#include <hip/hip_runtime.h>
#include <math.h>

#define HW    4096
#define C_CH  2048
#define B_N   8
#define BN_EPS 1e-5f

typedef float f32x4 __attribute__((ext_vector_type(4)));

// ---------------------------------------------------------------------------
// Kernel 1: per-(b,c) mean / max / unbiased std over HW=4096 elements.
// One WAVE per (b,c): 64 lanes x 16 float4 = 4096 elems. Pure shuffle
// reduction — no LDS, no __syncthreads. 4 waves (4 channels) per block.
// Double accumulation avoids cancellation in sumsq - sum^2/n.
// ---------------------------------------------------------------------------
__global__ __launch_bounds__(256) void stats_kernel(const float* __restrict__ x,
                                                    float* __restrict__ u) {
    const int wave = threadIdx.x >> 6;
    const int lane = threadIdx.x & 63;
    const int bc   = blockIdx.x * 4 + wave;
    const float4* xb = (const float4*)(x + (size_t)bc * HW);

    double sum = 0.0, sumsq = 0.0;
    float mx = -INFINITY;
#pragma unroll
    for (int i = 0; i < 16; ++i) {
        float4 v = xb[lane + i * 64];
        sum   += (double)v.x + (double)v.y + (double)v.z + (double)v.w;
        sumsq += (double)v.x * v.x + (double)v.y * v.y +
                 (double)v.z * v.z + (double)v.w * v.w;
        mx = fmaxf(mx, fmaxf(fmaxf(v.x, v.y), fmaxf(v.z, v.w)));
    }

#pragma unroll
    for (int off = 32; off > 0; off >>= 1) {
        sum   += __shfl_down(sum, off);
        sumsq += __shfl_down(sumsq, off);
        mx = fmaxf(mx, __shfl_down(mx, off));
    }

    if (lane == 0) {
        double mean = sum / (double)HW;
        double var  = (sumsq - sum * sum / (double)HW) / (double)(HW - 1);
        if (var < 0.0) var = 0.0;
        u[bc * 3 + 0] = (float)mean;
        u[bc * 3 + 1] = mx;
        u[bc * 3 + 2] = (float)sqrt(var);
    }
}

// ---------------------------------------------------------------------------
// Kernel 2: per batch b — exact median of u[b] (6144 vals) via 8-bit radix
// SELECT on sign-flipped float keys (order-preserving uint transform).
// np median of even count = mean of order stats 3071 & 3072 (0-based).
// 4 histogram levels per rank, 2 ranks: 8 passes over 24 KiB LDS instead of
// a 91-round bitonic sort. Then gate g[b,c] = sigmoid(BN(conv((u-med)^3))).
// ---------------------------------------------------------------------------
__global__ __launch_bounds__(256) void gate_kernel(const float* __restrict__ u,
                                                   const float* __restrict__ cfc_w,
                                                   const float* __restrict__ bn_w,
                                                   const float* __restrict__ bn_b,
                                                   float* __restrict__ g) {
    __shared__ unsigned int keys[C_CH * 3];   // 24 KiB
    __shared__ unsigned int hist[256];
    __shared__ unsigned int s_prefix, s_rank;

    const int b = blockIdx.x, t = threadIdx.x;
    const float* ub = u + (size_t)b * (C_CH * 3);

    // load + order-preserving float->uint transform
    for (int i = t; i < C_CH * 3; i += 256) {
        unsigned int k = __float_as_uint(ub[i]);
        keys[i] = (k & 0x80000000u) ? ~k : (k | 0x80000000u);
    }
    __syncthreads();

    float med_vals[2];
#pragma unroll
    for (int which = 0; which < 2; ++which) {
        unsigned int prefix = 0;                  // resolved high bits
        unsigned int rank   = 3071u + (unsigned)which;
        for (int shift = 24; shift >= 0; shift -= 8) {
            hist[t] = 0;                          // 256 threads == 256 bins
            __syncthreads();
            const unsigned int mask =
                (shift == 24) ? 0u : (0xFFFFFFFFu << (shift + 8));
            for (int i = t; i < C_CH * 3; i += 256) {
                const unsigned int k = keys[i];
                if ((k & mask) == prefix)
                    atomicAdd(&hist[(k >> shift) & 255u], 1u);
            }
            __syncthreads();
            if (t == 0) {
                unsigned int cum = 0;
                for (int bin = 0; bin < 256; ++bin) {
                    const unsigned int c = hist[bin];
                    if (rank < cum + c) {
                        s_prefix = prefix | ((unsigned int)bin << shift);
                        s_rank   = rank - cum;
                        break;
                    }
                    cum += c;
                }
            }
            __syncthreads();
            prefix = s_prefix;
            rank   = s_rank;
        }
        // prefix is the full 32-bit key of the order statistic; invert transform
        const unsigned int k = prefix;
        med_vals[which] =
            __uint_as_float((k & 0x80000000u) ? (k ^ 0x80000000u) : ~k);
    }

    const float med = 0.5f * (med_vals[0] + med_vals[1]);
    const float inv = rsqrtf(1.0f + BN_EPS);

    for (int c = t; c < C_CH; c += 256) {
        float d0 = ub[c * 3 + 0] - med;
        float d1 = ub[c * 3 + 1] - med;
        float d2 = ub[c * 3 + 2] - med;
        float z = d0 * d0 * d0 * cfc_w[c * 3 + 0] +
                  d1 * d1 * d1 * cfc_w[c * 3 + 1] +
                  d2 * d2 * d2 * cfc_w[c * 3 + 2];
        z = z * inv * bn_w[c] + bn_b[c];
        g[b * C_CH + c] = 1.0f / (1.0f + expf(-z));
    }
}

// ---------------------------------------------------------------------------
// Kernel 3: out = x * g[b,c]. One float4 per thread; g index (v>>10) is
// wave-uniform. NONTEMPORAL stores keep x resident in the 256 MiB Infinity
// Cache (it was just streamed by stats_kernel) so the re-read of x is an
// L3 hit instead of a second HBM fetch.
// ---------------------------------------------------------------------------
__global__ __launch_bounds__(256) void apply_kernel(const float* __restrict__ x,
                                                    const float* __restrict__ g,
                                                    float* __restrict__ out) {
    const size_t v = (size_t)blockIdx.x * 256 + threadIdx.x;  // float4 index
    const float gg = g[v >> 10];                              // 1024 f4 per (b,c)
    const f32x4 xv = ((const f32x4*)x)[v];
    const f32x4 o  = xv * gg;
    __builtin_nontemporal_store(o, &((f32x4*)out)[v]);
}

extern "C" void kernel_launch(void* const* d_in, const int* in_sizes, int n_in,
                              void* d_out, int out_size, void* d_ws, size_t ws_size,
                              hipStream_t stream) {
    const float* x     = (const float*)d_in[0];
    const float* cfc_w = (const float*)d_in[1];
    const float* bn_w  = (const float*)d_in[2];
    const float* bn_b  = (const float*)d_in[3];
    float* out = (float*)d_out;

    float* u = (float*)d_ws;               // [B, C, 3]  = 49152 floats
    float* g = u + (size_t)B_N * C_CH * 3; // [B, C]     = 16384 floats

    stats_kernel<<<(B_N * C_CH) / 4, 256, 0, stream>>>(x, u);
    gate_kernel<<<B_N, 256, 0, stream>>>(u, cfc_w, bn_w, bn_b, g);

    const int total_f4 = (B_N * C_CH * HW) / 4;          // 16,777,216
    apply_kernel<<<total_f4 / 256, 256, 0, stream>>>(x, g, out);
}

// Round 2
// 586.619 us; speedup vs baseline: 1.0020x; 1.0020x over previous
//
#include <hip/hip_runtime.h>
#include <math.h>

#define HW    4096
#define C_CH  2048
#define B_N   8
#define BN_EPS 1e-5f

typedef float f32x4 __attribute__((ext_vector_type(4)));

// ---------------------------------------------------------------------------
// Kernel 1: per-(b,c) mean / max / unbiased std over HW=4096 elements.
// One WAVE per (b,c): 64 lanes x 16 float4 = 4096 elems. Pure shuffle
// reduction — no LDS, no __syncthreads. 4 waves (4 channels) per block.
// Double accumulation avoids cancellation in sumsq - sum^2/n.
// Reads x front-to-back: on exit the Infinity Cache (256 MiB) holds the
// TAIL of x (268 MB) — apply_kernel exploits this by reading backward.
// ---------------------------------------------------------------------------
__global__ __launch_bounds__(256) void stats_kernel(const float* __restrict__ x,
                                                    float* __restrict__ u) {
    const int wave = threadIdx.x >> 6;
    const int lane = threadIdx.x & 63;
    const int bc   = blockIdx.x * 4 + wave;
    const float4* xb = (const float4*)(x + (size_t)bc * HW);

    double sum = 0.0, sumsq = 0.0;
    float mx = -INFINITY;
#pragma unroll
    for (int i = 0; i < 16; ++i) {
        float4 v = xb[lane + i * 64];
        sum   += (double)v.x + (double)v.y + (double)v.z + (double)v.w;
        sumsq += (double)v.x * v.x + (double)v.y * v.y +
                 (double)v.z * v.z + (double)v.w * v.w;
        mx = fmaxf(mx, fmaxf(fmaxf(v.x, v.y), fmaxf(v.z, v.w)));
    }

#pragma unroll
    for (int off = 32; off > 0; off >>= 1) {
        sum   += __shfl_down(sum, off);
        sumsq += __shfl_down(sumsq, off);
        mx = fmaxf(mx, __shfl_down(mx, off));
    }

    if (lane == 0) {
        double mean = sum / (double)HW;
        double var  = (sumsq - sum * sum / (double)HW) / (double)(HW - 1);
        if (var < 0.0) var = 0.0;
        u[bc * 3 + 0] = (float)mean;
        u[bc * 3 + 1] = mx;
        u[bc * 3 + 2] = (float)sqrt(var);
    }
}

// ---------------------------------------------------------------------------
// Kernel 2: per batch b — exact median of u[b] (6144 vals) via 8-bit radix
// SELECT on sign-flipped float keys (order-preserving uint transform).
// np median of even count = mean of order stats 3071 & 3072 (0-based).
// Then gate g[b,c] = sigmoid(BN(conv((u-med)^3))).
// ---------------------------------------------------------------------------
__global__ __launch_bounds__(256) void gate_kernel(const float* __restrict__ u,
                                                   const float* __restrict__ cfc_w,
                                                   const float* __restrict__ bn_w,
                                                   const float* __restrict__ bn_b,
                                                   float* __restrict__ g) {
    __shared__ unsigned int keys[C_CH * 3];   // 24 KiB
    __shared__ unsigned int hist[256];
    __shared__ unsigned int s_prefix, s_rank;

    const int b = blockIdx.x, t = threadIdx.x;
    const float* ub = u + (size_t)b * (C_CH * 3);

    // load + order-preserving float->uint transform
    for (int i = t; i < C_CH * 3; i += 256) {
        unsigned int k = __float_as_uint(ub[i]);
        keys[i] = (k & 0x80000000u) ? ~k : (k | 0x80000000u);
    }
    __syncthreads();

    float med_vals[2];
#pragma unroll
    for (int which = 0; which < 2; ++which) {
        unsigned int prefix = 0;                  // resolved high bits
        unsigned int rank   = 3071u + (unsigned)which;
        for (int shift = 24; shift >= 0; shift -= 8) {
            hist[t] = 0;                          // 256 threads == 256 bins
            __syncthreads();
            const unsigned int mask =
                (shift == 24) ? 0u : (0xFFFFFFFFu << (shift + 8));
            for (int i = t; i < C_CH * 3; i += 256) {
                const unsigned int k = keys[i];
                if ((k & mask) == prefix)
                    atomicAdd(&hist[(k >> shift) & 255u], 1u);
            }
            __syncthreads();
            if (t == 0) {
                unsigned int cum = 0;
                for (int bin = 0; bin < 256; ++bin) {
                    const unsigned int c = hist[bin];
                    if (rank < cum + c) {
                        s_prefix = prefix | ((unsigned int)bin << shift);
                        s_rank   = rank - cum;
                        break;
                    }
                    cum += c;
                }
            }
            __syncthreads();
            prefix = s_prefix;
            rank   = s_rank;
        }
        const unsigned int k = prefix;
        med_vals[which] =
            __uint_as_float((k & 0x80000000u) ? (k ^ 0x80000000u) : ~k);
    }

    const float med = 0.5f * (med_vals[0] + med_vals[1]);
    const float inv = rsqrtf(1.0f + BN_EPS);

    for (int c = t; c < C_CH; c += 256) {
        float d0 = ub[c * 3 + 0] - med;
        float d1 = ub[c * 3 + 1] - med;
        float d2 = ub[c * 3 + 2] - med;
        float z = d0 * d0 * d0 * cfc_w[c * 3 + 0] +
                  d1 * d1 * d1 * cfc_w[c * 3 + 1] +
                  d2 * d2 * d2 * cfc_w[c * 3 + 2];
        z = z * inv * bn_w[c] + bn_b[c];
        g[b * C_CH + c] = 1.0f / (1.0f + expf(-z));
    }
}

// ---------------------------------------------------------------------------
// Kernel 3: out = x * g[b,c]. One float4 per thread.
// REVERSE block order: stats_kernel just streamed x front-to-back, so the
// Infinity Cache holds the TAIL of x. Reading backward chases the resident
// region (L3 hits) instead of evicting the next line we need. Nontemporal
// stores keep the out-stream from evicting x.
// ---------------------------------------------------------------------------
__global__ __launch_bounds__(256) void apply_kernel(const float* __restrict__ x,
                                                    const float* __restrict__ g,
                                                    float* __restrict__ out) {
    const size_t blk = (size_t)(gridDim.x - 1 - blockIdx.x);
    const size_t v = blk * 256 + threadIdx.x;                 // float4 index
    const float gg = g[v >> 10];                              // 1024 f4 per (b,c)
    const f32x4 xv = ((const f32x4*)x)[v];
    const f32x4 o  = xv * gg;
    __builtin_nontemporal_store(o, &((f32x4*)out)[v]);
}

extern "C" void kernel_launch(void* const* d_in, const int* in_sizes, int n_in,
                              void* d_out, int out_size, void* d_ws, size_t ws_size,
                              hipStream_t stream) {
    const float* x     = (const float*)d_in[0];
    const float* cfc_w = (const float*)d_in[1];
    const float* bn_w  = (const float*)d_in[2];
    const float* bn_b  = (const float*)d_in[3];
    float* out = (float*)d_out;

    float* u = (float*)d_ws;               // [B, C, 3]  = 49152 floats
    float* g = u + (size_t)B_N * C_CH * 3; // [B, C]     = 16384 floats

    stats_kernel<<<(B_N * C_CH) / 4, 256, 0, stream>>>(x, u);
    gate_kernel<<<B_N, 256, 0, stream>>>(u, cfc_w, bn_w, bn_b, g);

    const int total_f4 = (B_N * C_CH * HW) / 4;          // 16,777,216
    apply_kernel<<<total_f4 / 256, 256, 0, stream>>>(x, g, out);
}